// Round 14
// baseline (145.113 us; speedup 1.0000x reference)
//
#include <hip/hip_runtime.h>
#include <hip/hip_bf16.h>

#define CC 20480      // columns of X
#define PP 2048       // P
#define NROWS 2047    // rows reduced
#define SRR 10
#define HH 1024
#define NCH 64        // row chunks (32 rows each)

typedef __attribute__((ext_vector_type(8))) short short8;
typedef __attribute__((ext_vector_type(4))) float f32x4;

// ---------------- split helper ----------------------------------------
__device__ __forceinline__ void split_bf16(float v, unsigned short& hi, unsigned short& lo) {
    __hip_bfloat16 h = __float2bfloat16(v);
    float r = v - __bfloat162float(h);
    __hip_bfloat16 l2 = __float2bfloat16(r);
    hi = *(unsigned short*)&h;
    lo = *(unsigned short*)&l2;
}

// ---------------- pre: colsum + W2->W2T + W3 split + threshold sort ----
// blocks 0..511: colsum; 512..767: W2 transpose (fp32); 768..1023: W3
// split; block 1024: bitonic-sort layer-1 relu thresholds.
__global__ __launch_bounds__(256) void pre_k(const float* __restrict__ X,
                                             const int* __restrict__ p,
                                             float* __restrict__ psum,
                                             const float* __restrict__ W2,
                                             float* __restrict__ w2t,
                                             const float* __restrict__ W3,
                                             unsigned short* __restrict__ w3h,
                                             unsigned short* __restrict__ w3l,
                                             const float* __restrict__ W1,
                                             const float* __restrict__ b1,
                                             float* __restrict__ tsort,
                                             int* __restrict__ ord,
                                             float* __restrict__ cA,
                                             float* __restrict__ cC,
                                             float* __restrict__ cI,
                                             float* __restrict__ cIC) {
    int b = blockIdx.x, t = threadIdx.x;
    if (b < 512) {
        int k = (b & 7) * 256 + t;
        int chunk = b >> 3;
        int r0 = chunk * 32;
        int r1 = r0 + 32; if (r1 > NROWS) r1 = NROWS;
        float s = 0.f;
        int base = SRR * k;
        for (int i = r0; i < r1; ++i) {
            int col = base - p[i]; if (col < 0) col += CC;   // p[i] in [0,64)
            s += X[(size_t)i * (size_t)(SRR * CC) + col];
        }
        psum[chunk * PP + k] = s;
        return;
    }
    if (b < 768) {                    // W2 -> W2T (fp32)
        int bb = b - 512;
        int idx = bb * 4096 + t * 16;
        int n2 = idx >> 10;
        int o0 = idx & 1023;
        #pragma unroll
        for (int q = 0; q < 4; ++q) {
            float4 v = *(const float4*)&W2[idx + q * 4];
            w2t[(size_t)(o0 + q * 4 + 0) * 1024 + n2] = v.x;
            w2t[(size_t)(o0 + q * 4 + 1) * 1024 + n2] = v.y;
            w2t[(size_t)(o0 + q * 4 + 2) * 1024 + n2] = v.z;
            w2t[(size_t)(o0 + q * 4 + 3) * 1024 + n2] = v.w;
        }
        return;
    }
    if (b < 1024) {                   // W3 split (unchanged)
        int bb = b - 768;
        int idx = bb * 4096 + t * 16;
        #pragma unroll
        for (int q = 0; q < 4; ++q) {
            float4 v = *(const float4*)&W3[idx + q * 4];
            float vv[4] = {v.x, v.y, v.z, v.w};
            ushort hi4[4], lo4[4];
            #pragma unroll
            for (int i = 0; i < 4; ++i) split_bf16(vv[i], hi4[i], lo4[i]);
            *(ushort4*)&w3h[idx + q * 4] = *(ushort4*)hi4;
            *(ushort4*)&w3l[idx + q * 4] = *(ushort4*)lo4;
        }
        return;
    }
    // ---- sort block: thresholds t_o, families, coefficient arrays ----
    __shared__ float ks[1024];
    __shared__ int vs[1024];
    const float PINF = __int_as_float(0x7f800000);
    for (int i = t; i < 1024; i += 256) {
        float w1 = W1[i], bv = b1[i];
        float tv;
        if (w1 != 0.f) tv = -bv / w1;
        else tv = (bv > 0.f) ? -PINF : PINF;   // always / never active
        ks[i] = tv; vs[i] = i;
    }
    __syncthreads();
    for (int size = 2; size <= 1024; size <<= 1)
        for (int stride = size >> 1; stride; stride >>= 1) {
            for (int i = t; i < 1024; i += 256) {
                int jx = i ^ stride;
                if (jx > i) {
                    bool up = ((i & size) == 0);
                    float a = ks[i], bq = ks[jx];
                    bool sw = up ? (a > bq) : (a < bq);
                    if (sw) {
                        ks[i] = bq; ks[jx] = a;
                        int tmp = vs[i]; vs[i] = vs[jx]; vs[jx] = tmp;
                    }
                }
            }
            __syncthreads();
        }
    for (int i = t; i < 1024; i += 256) {
        int o = vs[i];
        float w1 = W1[o], bv = b1[o];
        float s = (w1 < 0.f) ? -1.f : 1.f;     // fam- iff W1<0
        tsort[i] = ks[i]; ord[i] = o;
        cA[i] = s * w1;  cC[i] = s * bv;       // signed flip deltas
        cI[i] = (w1 < 0.f) ? w1 : 0.f;         // init (x->-inf): fam- active
        cIC[i] = (w1 < 0.f) ? bv : 0.f;
    }
}

// ---------------- scan: build Atab/Ctab[1025][1024] + xcalc ------------
// blocks 0..15: block b owns n2 in [b*64,b*64+64); thread (q=t>>6,n=t&63)
// scans j in [q*256,q*256+256). Pass1: totals; Pass2: write final tables.
// blocks 16..23: x[k] = psum reduce.
__global__ __launch_bounds__(256) void scan_k(const float* __restrict__ w2t,
                                              const int* __restrict__ ord,
                                              const float* __restrict__ cA,
                                              const float* __restrict__ cC,
                                              const float* __restrict__ cI,
                                              const float* __restrict__ cIC,
                                              float* __restrict__ Atab,
                                              float* __restrict__ Ctab,
                                              const float* __restrict__ psum,
                                              float* __restrict__ xbuf) {
    int b = blockIdx.x, t = threadIdx.x;
    if (b >= 16) {
        int k = (b - 16) * 256 + t;
        float s = 0.f;
        #pragma unroll 8
        for (int c = 0; c < NCH; ++c) s += psum[c * PP + k];
        xbuf[k] = s * (1.0f / (float)NROWS);
        return;
    }
    __shared__ float sA[4][64], sC[4][64], sIA[4][64], sIC[4][64];
    int q = t >> 6, n = t & 63;
    int n2 = b * 64 + n;
    float gA = 0.f, gC = 0.f, iA = 0.f, iC = 0.f;
    #pragma unroll 4
    for (int step = 0; step < 256; ++step) {
        int j = q * 256 + step;
        int o = ord[j];
        float wv = w2t[(size_t)o * 1024 + n2];
        gA = fmaf(cA[j], wv, gA);
        gC = fmaf(cC[j], wv, gC);
        iA = fmaf(cI[j], wv, iA);
        iC = fmaf(cIC[j], wv, iC);
    }
    sA[q][n] = gA; sC[q][n] = gC; sIA[q][n] = iA; sIC[q][n] = iC;
    __syncthreads();
    float offA = sIA[0][n] + sIA[1][n] + sIA[2][n] + sIA[3][n];
    float offC = sIC[0][n] + sIC[1][n] + sIC[2][n] + sIC[3][n];
    #pragma unroll
    for (int q2 = 0; q2 < 4; ++q2)
        if (q2 < q) { offA += sA[q2][n]; offC += sC[q2][n]; }
    if (q == 0) { Atab[n2] = offA; Ctab[n2] = offC; }   // slot 0 = init
    float g2 = offA, h2 = offC;
    #pragma unroll 4
    for (int step = 0; step < 256; ++step) {
        int j = q * 256 + step;
        int o = ord[j];
        float wv = w2t[(size_t)o * 1024 + n2];
        g2 = fmaf(cA[j], wv, g2);
        h2 = fmaf(cC[j], wv, h2);
        Atab[(size_t)(j + 1) * 1024 + n2] = g2;
        Ctab[(size_t)(j + 1) * 1024 + n2] = h2;
    }
}

// ---------------- evalh2: h2[k] = relu(A[jk]*x + C[jk] + b2) -----------
__global__ __launch_bounds__(512) void evalh2_k(const float* __restrict__ tsort,
                                                const float* __restrict__ Atab,
                                                const float* __restrict__ Ctab,
                                                const float* __restrict__ b2,
                                                const float* __restrict__ xbuf,
                                                unsigned short* __restrict__ h2h,
                                                unsigned short* __restrict__ h2l) {
    __shared__ float ts[1024];
    int t = threadIdx.x;
    for (int i = t; i < 1024; i += 512) ts[i] = tsort[i];
    __syncthreads();
    int wv = t >> 6, lane = t & 63;
    int k = blockIdx.x * 8 + wv;
    float x = xbuf[k];
    int lo = 0, hi = 1024;                 // j = count(t < x)
    while (lo < hi) { int mid = (lo + hi) >> 1; if (ts[mid] < x) lo = mid + 1; else hi = mid; }
    const float* Ac = Atab + (size_t)lo * 1024;
    const float* Cc = Ctab + (size_t)lo * 1024;
    #pragma unroll
    for (int s2 = 0; s2 < 16; ++s2) {
        int n2 = s2 * 64 + lane;
        float a = Ac[n2], c = Cc[n2], bb = b2[n2];
        float h = fmaf(a, x, c + bb);
        h = h > 0.f ? h : 0.f;
        unsigned short hh, hl;
        split_bf16(h, hh, hl);
        h2h[(size_t)k * 1024 + n2] = hh;
        h2l[(size_t)k * 1024 + n2] = hl;
    }
}

// ---------------- async global->LDS, 16B/lane -------------------------
__device__ __forceinline__ void gload16(const unsigned short* g, unsigned short* lds) {
    __builtin_amdgcn_global_load_lds(
        (const __attribute__((address_space(1))) void*)g,
        (__attribute__((address_space(3))) void*)lds,
        16, 0, 0);
}

#define BM 128
#define BN 64
#define BK 32

// ======================================================================
// GEMM2: partial = (relu(h2 @ W3^T + b3)) . W4 fused. Triple-buffered
// counted-vmcnt pipeline (R13, 81.9 us best).
// ======================================================================
__global__ __launch_bounds__(512, 2) void gemm2_k(
    const unsigned short* __restrict__ Ah, const unsigned short* __restrict__ Al,
    const unsigned short* __restrict__ Bh, const unsigned short* __restrict__ Bl,
    const float* __restrict__ b3,
    const float* __restrict__ W4, float* __restrict__ partial)
{
    __shared__ unsigned short lds[3][12288];   // 72 KB
    int lin = blockIdx.x;
    int v = (lin & 7) * 32 + (lin >> 3);
    int bx = v >> 4, by = v & 15;
    int bm = bx * BM, bn = by * BN;
    int t = threadIdx.x, w = t >> 6, l = t & 63;
    int lr = l & 15, lk = l >> 4;
    int wr = w >> 1, wc = w & 1;

    size_t offA = (size_t)(bm + w * 16 + lr) * HH + lk * 8;
    size_t offB = (size_t)(bn + (w & 3) * 16 + lr) * HH + lk * 8;

#define STAGE(buf, k0)                                                   \
    do {                                                                 \
        unsigned short* L = lds[buf];                                    \
        gload16(Ah + offA + (k0), L + w * 512);                          \
        gload16(Al + offA + (k0), L + 4096 + w * 512);                   \
        if (w < 4) gload16(Bh + offB + (k0), L + 8192 + w * 512);        \
        else       gload16(Bl + offB + (k0), L + 10240 + (w - 4) * 512); \
    } while (0)

    f32x4 acc[2][2];
    #pragma unroll
    for (int i = 0; i < 2; ++i)
        #pragma unroll
        for (int j = 0; j < 2; ++j) acc[i][j] = (f32x4)(0.f);

    STAGE(0, 0);

    int nt = HH / BK;
    for (int tt = 0; tt < nt; ++tt) {
        int cur = tt % 3;
        if (tt + 1 < nt) {
            STAGE((tt + 1) % 3, (tt + 1) * BK);
            asm volatile("s_waitcnt vmcnt(3)" ::: "memory");
        } else {
            asm volatile("s_waitcnt vmcnt(0)" ::: "memory");
        }
        __builtin_amdgcn_s_barrier();
        __builtin_amdgcn_sched_barrier(0);
        __builtin_amdgcn_s_setprio(1);
        unsigned short* L = lds[cur];
        short8 ah2[2], al2[2], bh2[2], bl2[2];
        #pragma unroll
        for (int mi = 0; mi < 2; ++mi) {
            ah2[mi] = *(const short8*)&L[(wr * 2 + mi) * 512 + l * 8];
            al2[mi] = *(const short8*)&L[4096 + (wr * 2 + mi) * 512 + l * 8];
        }
        #pragma unroll
        for (int ni = 0; ni < 2; ++ni) {
            bh2[ni] = *(const short8*)&L[8192 + (wc * 2 + ni) * 512 + l * 8];
            bl2[ni] = *(const short8*)&L[10240 + (wc * 2 + ni) * 512 + l * 8];
        }
        #pragma unroll
        for (int mi = 0; mi < 2; ++mi)
            #pragma unroll
            for (int ni = 0; ni < 2; ++ni) {
                acc[mi][ni] = __builtin_amdgcn_mfma_f32_16x16x32_bf16(ah2[mi], bh2[ni], acc[mi][ni], 0, 0, 0);
                acc[mi][ni] = __builtin_amdgcn_mfma_f32_16x16x32_bf16(ah2[mi], bl2[ni], acc[mi][ni], 0, 0, 0);
                acc[mi][ni] = __builtin_amdgcn_mfma_f32_16x16x32_bf16(al2[mi], bh2[ni], acc[mi][ni], 0, 0, 0);
            }
        __builtin_amdgcn_s_setprio(0);
        __builtin_amdgcn_sched_barrier(0);
    }
#undef STAGE

    float bv[2], w4v[2];
    #pragma unroll
    for (int ni = 0; ni < 2; ++ni) {
        bv[ni]  = b3[bn + wc * 32 + ni * 16 + lr];
        w4v[ni] = W4[bn + wc * 32 + ni * 16 + lr];
    }
    #pragma unroll
    for (int mi = 0; mi < 2; ++mi) {
        float ps[4];
        #pragma unroll
        for (int r = 0; r < 4; ++r) {
            float acc_d = 0.f;
            #pragma unroll
            for (int ni = 0; ni < 2; ++ni) {
                float vv = acc[mi][ni][r] + bv[ni];
                vv = vv > 0.f ? vv : 0.f;
                acc_d += vv * w4v[ni];
            }
            ps[r] = acc_d;
        }
        #pragma unroll
        for (int r = 0; r < 4; ++r) {
            #pragma unroll
            for (int m2 = 1; m2 < 16; m2 <<= 1) ps[r] += __shfl_xor(ps[r], m2, 64);
        }
        if (lr == 0) {
            #pragma unroll
            for (int r = 0; r < 4; ++r) {
                int row = bm + wr * 32 + mi * 16 + lk * 4 + r;
                partial[(size_t)row * 32 + by * 2 + wc] = ps[r];
            }
        }
    }
}

// ---------------- ysum: y[r] = sum(partial[r][:]) + b4 ----------------
__global__ __launch_bounds__(256) void ysum_k(const float* __restrict__ partial,
                                              const float* __restrict__ b4,
                                              float* __restrict__ y) {
    int r = blockIdx.x * 256 + threadIdx.x;
    float s = 0.f;
    #pragma unroll
    for (int q = 0; q < 8; ++q) {
        float4 v = *(const float4*)&partial[(size_t)r * 32 + q * 4];
        s += v.x + v.y + v.z + v.w;
    }
    y[r] = s + b4[0];
}

extern "C" void kernel_launch(void* const* d_in, const int* in_sizes, int n_in,
                              void* d_out, int out_size, void* d_ws, size_t ws_size,
                              hipStream_t stream) {
    const float* X  = (const float*)d_in[0];
    const int*   p  = (const int*)d_in[1];
    const float* W1 = (const float*)d_in[2];
    const float* b1 = (const float*)d_in[3];
    const float* W2 = (const float*)d_in[4];
    const float* b2 = (const float*)d_in[5];
    const float* W3 = (const float*)d_in[6];
    const float* b3 = (const float*)d_in[7];
    const float* W4 = (const float*)d_in[8];
    const float* b4 = (const float*)d_in[9];
    float* out = (float*)d_out;

    char* ws = (char*)d_ws;
    size_t off = 0;
    float* psum  = (float*)(ws + off); off += (size_t)NCH * PP * 4;         // 512 KB
    float* xbuf  = (float*)(ws + off); off += 8192;
    float* w2t   = (float*)(ws + off); off += (size_t)HH * HH * 4;          // 4 MB
    unsigned short* w3h = (unsigned short*)(ws + off); off += (size_t)HH * HH * 2;
    unsigned short* w3l = (unsigned short*)(ws + off); off += (size_t)HH * HH * 2;
    float* tsort = (float*)(ws + off); off += 4096;
    int*   ordb  = (int*)  (ws + off); off += 4096;
    float* cA    = (float*)(ws + off); off += 4096;
    float* cC    = (float*)(ws + off); off += 4096;
    float* cI    = (float*)(ws + off); off += 4096;
    float* cIC   = (float*)(ws + off); off += 4096;
    float* Atab  = (float*)(ws + off); off += (size_t)1025 * 1024 * 4;      // 4.2 MB
    float* Ctab  = (float*)(ws + off); off += (size_t)1025 * 1024 * 4;
    unsigned short* h2h = (unsigned short*)(ws + off); off += (size_t)PP * HH * 2;
    unsigned short* h2l = (unsigned short*)(ws + off); off += (size_t)PP * HH * 2;
    float* partial = (float*)(ws + off); off += (size_t)PP * 32 * 4;

    pre_k<<<1025, 256, 0, stream>>>(X, p, psum, W2, w2t, W3, w3h, w3l,
                                    W1, b1, tsort, ordb, cA, cC, cI, cIC);
    scan_k<<<24, 256, 0, stream>>>(w2t, ordb, cA, cC, cI, cIC, Atab, Ctab, psum, xbuf);
    evalh2_k<<<256, 512, 0, stream>>>(tsort, Atab, Ctab, b2, xbuf, h2h, h2l);
    gemm2_k<<<256, 512, 0, stream>>>(h2h, h2l, w3h, w3l, b3, W4, partial);
    ysum_k<<<PP / 256, 256, 0, stream>>>(partial, b4, out);
}

// Round 15
// 80.193 us; speedup vs baseline: 1.8095x; 1.8095x over previous
//
#include <hip/hip_runtime.h>
#include <hip/hip_bf16.h>

#define CC 20480      // columns of X
#define PP 2048       // P
#define NROWS 2047    // rows reduced
#define SRR 10
#define HH 1024
#define NCH 64        // row chunks (32 rows each)

typedef __attribute__((ext_vector_type(8))) short short8;
typedef __attribute__((ext_vector_type(4))) float f32x4;

// ---------------- split helper ----------------------------------------
__device__ __forceinline__ void split_bf16(float v, unsigned short& hi, unsigned short& lo) {
    __hip_bfloat16 h = __float2bfloat16(v);
    float r = v - __bfloat162float(h);
    __hip_bfloat16 l2 = __float2bfloat16(r);
    hi = *(unsigned short*)&h;
    lo = *(unsigned short*)&l2;
}

// ---------------- pre: colsum gather (blocks 0..511) + wconv -----------
__global__ __launch_bounds__(256) void pre_k(const float* __restrict__ X,
                                             const int* __restrict__ p,
                                             float* __restrict__ psum,
                                             const float* __restrict__ W2,
                                             unsigned short* __restrict__ w2h,
                                             unsigned short* __restrict__ w2l,
                                             const float* __restrict__ W3,
                                             unsigned short* __restrict__ w3h,
                                             unsigned short* __restrict__ w3l) {
    int b = blockIdx.x, t = threadIdx.x;
    if (b < 512) {
        int k = (b & 7) * 256 + t;              // 0..2047
        int chunk = b >> 3;                     // 0..63
        int r0 = chunk * 32;
        int r1 = r0 + 32; if (r1 > NROWS) r1 = NROWS;
        float s = 0.f;
        int base = SRR * k;
        for (int i = r0; i < r1; ++i) {
            int col = base - p[i]; if (col < 0) col += CC;   // p[i] in [0,64)
            s += X[(size_t)i * (size_t)(SRR * CC) + col];
        }
        psum[chunk * PP + k] = s;
        return;
    }
    int bb = b - 512;
    const float* src; unsigned short *dh, *dl;
    if (bb < 256) { src = W2; dh = w2h; dl = w2l; }
    else { src = W3; dh = w3h; dl = w3l; bb -= 256; }
    int idx = bb * 4096 + t * 16;
    #pragma unroll
    for (int q = 0; q < 4; ++q) {
        float4 v = *(const float4*)&src[idx + q * 4];
        float vv[4] = {v.x, v.y, v.z, v.w};
        ushort hi4[4], lo4[4];
        #pragma unroll
        for (int i = 0; i < 4; ++i) split_bf16(vv[i], hi4[i], lo4[i]);
        *(ushort4*)&dh[idx + q * 4] = *(ushort4*)hi4;
        *(ushort4*)&dl[idx + q * 4] = *(ushort4*)lo4;
    }
}

// ---------------- async global->LDS, 16B/lane -------------------------
__device__ __forceinline__ void gload16(const unsigned short* g, unsigned short* lds) {
    __builtin_amdgcn_global_load_lds(
        (const __attribute__((address_space(1))) void*)g,
        (__attribute__((address_space(3))) void*)lds,
        16, 0, 0);
}

#define BM 128
#define BN 64
#define BK 64

// ======================================================================
// GEMM1: h2 = relu(h1 @ W2^T + b2), h1 = relu(x*W1+b1) generated on the
// fly. B via global_load_lds. BK=64 (2 k-slices/step, 16 steps), triple-
// buffered, 1 barrier + vmcnt(2) per step.
// ======================================================================
__global__ __launch_bounds__(512, 2) void gemm1_k(
    const float* __restrict__ psum,
    const float* __restrict__ W1, const float* __restrict__ b1,
    const unsigned short* __restrict__ Bh, const unsigned short* __restrict__ Bl,
    const float* __restrict__ b2,
    unsigned short* __restrict__ Ch, unsigned short* __restrict__ Cl)
{
    __shared__ unsigned short Bb[3][8192];   // per buf: hi [0,4096), lo [4096,8192)
    __shared__ float w1f[1024], b1f[1024], xv[128];

    int lin = blockIdx.x;
    int v = (lin & 7) * 32 + (lin >> 3);     // XCD-chunked, grid=256
    int bx = v >> 4, by = v & 15;
    int bm = bx * BM, bn = by * BN;
    int t = threadIdx.x, w = t >> 6, l = t & 63;
    int lr = l & 15, lk = l >> 4;
    int wr = w >> 1, wc = w & 1;

    // wave w stages B chunk (g=w>>1, s=w&1): rows bn+g*16+lr, k=s*32+lk*8
    size_t offB = (size_t)(bn + (w >> 1) * 16 + lr) * HH + (w & 1) * 32 + lk * 8;
#define BSTAGE(buf, k0)                                         \
    do {                                                        \
        gload16(Bh + offB + (k0), Bb[buf] + w * 512);           \
        gload16(Bl + offB + (k0), Bb[buf] + 4096 + w * 512);    \
    } while (0)

    BSTAGE(0, 0);
    // ---- prologue: xv, W1/b1 to LDS ----
    {
        int row = t >> 2, q = t & 3;
        float s = 0.f;
        #pragma unroll
        for (int j = 0; j < 16; ++j) s += psum[(q * 16 + j) * PP + bm + row];
        s += __shfl_xor(s, 1, 64);
        s += __shfl_xor(s, 2, 64);
        if (q == 0) xv[row] = s * (1.0f / (float)NROWS);
        if (t < 256) *(float4*)&w1f[t * 4] = *(const float4*)&W1[t * 4];
        else *(float4*)&b1f[(t - 256) * 4] = *(const float4*)&b1[(t - 256) * 4];
    }
    __syncthreads();                         // xv/w1f/b1f + Bb[0] ready

    float x0 = xv[wr * 32 + lr], x1 = xv[wr * 32 + 16 + lr];

    f32x4 acc[2][2];
    #pragma unroll
    for (int i = 0; i < 2; ++i)
        #pragma unroll
        for (int j = 0; j < 2; ++j) acc[i][j] = (f32x4)(0.f);

    int nt = HH / BK;                        // 16
    for (int tt = 0; tt < nt; ++tt) {
        int cur = tt % 3;
        if (tt + 1 < nt) {
            BSTAGE((tt + 1) % 3, (tt + 1) * BK);
            asm volatile("s_waitcnt vmcnt(2)" ::: "memory");
        } else {
            asm volatile("s_waitcnt vmcnt(0)" ::: "memory");
        }
        __builtin_amdgcn_s_barrier();
        __builtin_amdgcn_sched_barrier(0);
        __builtin_amdgcn_s_setprio(1);
        #pragma unroll
        for (int s2 = 0; s2 < 2; ++s2) {
            int k0 = tt * BK + s2 * 32;
            float4 wva = *(const float4*)&w1f[k0 + lk * 8];
            float4 wvb = *(const float4*)&w1f[k0 + lk * 8 + 4];
            float4 bva = *(const float4*)&b1f[k0 + lk * 8];
            float4 bvb = *(const float4*)&b1f[k0 + lk * 8 + 4];
            float wv[8] = {wva.x, wva.y, wva.z, wva.w, wvb.x, wvb.y, wvb.z, wvb.w};
            float bv2[8] = {bva.x, bva.y, bva.z, bva.w, bvb.x, bvb.y, bvb.z, bvb.w};
            ushort ahh[2][8], all2[2][8];
            #pragma unroll
            for (int mi = 0; mi < 2; ++mi) {
                float xm = mi ? x1 : x0;
                #pragma unroll
                for (int j = 0; j < 8; ++j) {
                    float h = fmaf(xm, wv[j], bv2[j]);
                    h = h > 0.f ? h : 0.f;
                    split_bf16(h, ahh[mi][j], all2[mi][j]);
                }
            }
            short8 bh2[2], bl2[2];
            #pragma unroll
            for (int ni = 0; ni < 2; ++ni) {
                bh2[ni] = *(const short8*)&Bb[cur][((wc * 2 + ni) * 2 + s2) * 512 + l * 8];
                bl2[ni] = *(const short8*)&Bb[cur][4096 + ((wc * 2 + ni) * 2 + s2) * 512 + l * 8];
            }
            #pragma unroll
            for (int mi = 0; mi < 2; ++mi) {
                short8 ah2 = *(short8*)ahh[mi];
                short8 al2 = *(short8*)all2[mi];
                #pragma unroll
                for (int ni = 0; ni < 2; ++ni) {
                    acc[mi][ni] = __builtin_amdgcn_mfma_f32_16x16x32_bf16(ah2, bh2[ni], acc[mi][ni], 0, 0, 0);
                    acc[mi][ni] = __builtin_amdgcn_mfma_f32_16x16x32_bf16(ah2, bl2[ni], acc[mi][ni], 0, 0, 0);
                    acc[mi][ni] = __builtin_amdgcn_mfma_f32_16x16x32_bf16(al2, bh2[ni], acc[mi][ni], 0, 0, 0);
                }
            }
        }
        __builtin_amdgcn_s_setprio(0);
        __builtin_amdgcn_sched_barrier(0);
    }
#undef BSTAGE

    float bv[2];
    #pragma unroll
    for (int ni = 0; ni < 2; ++ni) bv[ni] = b2[bn + wc * 32 + ni * 16 + lr];
    #pragma unroll
    for (int mi = 0; mi < 2; ++mi)
        #pragma unroll
        for (int ni = 0; ni < 2; ++ni)
            #pragma unroll
            for (int r = 0; r < 4; ++r) {
                int row = bm + wr * 32 + mi * 16 + lk * 4 + r;
                int col = bn + wc * 32 + ni * 16 + lr;
                float vv = acc[mi][ni][r] + bv[ni];
                vv = vv > 0.f ? vv : 0.f;
                unsigned short hi, lo;
                split_bf16(vv, hi, lo);
                Ch[(size_t)row * HH + col] = hi;
                Cl[(size_t)row * HH + col] = lo;
            }
}

// ======================================================================
// GEMM2: partial = (relu(h2 @ W3^T + b3)) . W4 fused. A,B via
// global_load_lds. BK=64, triple-buffered (144 KB LDS), 1 barrier +
// vmcnt(6) per step, 16 steps.
// ======================================================================
__global__ __launch_bounds__(512, 2) void gemm2_k(
    const unsigned short* __restrict__ Ah, const unsigned short* __restrict__ Al,
    const unsigned short* __restrict__ Bh, const unsigned short* __restrict__ Bl,
    const float* __restrict__ b3,
    const float* __restrict__ W4, float* __restrict__ partial)
{
    __shared__ unsigned short lds[3][24576];   // 144 KB (gfx950: 160 KB/CU)
    // per buffer: A_hi [0,8192) chunks (g=w,s); A_lo [8192,16384);
    //             B_hi [16384,20480) chunks (g=w&3,s); B_lo [20480,24576)
    int lin = blockIdx.x;
    int v = (lin & 7) * 32 + (lin >> 3);
    int bx = v >> 4, by = v & 15;
    int bm = bx * BM, bn = by * BN;
    int t = threadIdx.x, w = t >> 6, l = t & 63;
    int lr = l & 15, lk = l >> 4;
    int wr = w >> 1, wc = w & 1;

    size_t offA = (size_t)(bm + w * 16 + lr) * HH + lk * 8;
    size_t offB = (size_t)(bn + (w & 3) * 16 + lr) * HH + lk * 8;

#define STAGE(buf, k0)                                                          \
    do {                                                                        \
        unsigned short* L = lds[buf];                                           \
        gload16(Ah + offA + (k0),      L + (w * 2 + 0) * 512);                  \
        gload16(Ah + offA + (k0) + 32, L + (w * 2 + 1) * 512);                  \
        gload16(Al + offA + (k0),      L + 8192 + (w * 2 + 0) * 512);           \
        gload16(Al + offA + (k0) + 32, L + 8192 + (w * 2 + 1) * 512);           \
        if (w < 4) {                                                            \
            gload16(Bh + offB + (k0),      L + 16384 + ((w & 3) * 2 + 0) * 512);\
            gload16(Bh + offB + (k0) + 32, L + 16384 + ((w & 3) * 2 + 1) * 512);\
        } else {                                                                \
            gload16(Bl + offB + (k0),      L + 20480 + ((w & 3) * 2 + 0) * 512);\
            gload16(Bl + offB + (k0) + 32, L + 20480 + ((w & 3) * 2 + 1) * 512);\
        }                                                                       \
    } while (0)

    f32x4 acc[2][2];
    #pragma unroll
    for (int i = 0; i < 2; ++i)
        #pragma unroll
        for (int j = 0; j < 2; ++j) acc[i][j] = (f32x4)(0.f);

    STAGE(0, 0);

    int nt = HH / BK;                      // 16 steps
    for (int tt = 0; tt < nt; ++tt) {
        int cur = tt % 3;
        if (tt + 1 < nt) {
            STAGE((tt + 1) % 3, (tt + 1) * BK);
            asm volatile("s_waitcnt vmcnt(6)" ::: "memory");
        } else {
            asm volatile("s_waitcnt vmcnt(0)" ::: "memory");
        }
        __builtin_amdgcn_s_barrier();
        __builtin_amdgcn_sched_barrier(0);
        __builtin_amdgcn_s_setprio(1);
        unsigned short* L = lds[cur];
        #pragma unroll
        for (int s2 = 0; s2 < 2; ++s2) {
            short8 ah2[2], al2[2], bh2[2], bl2[2];
            #pragma unroll
            for (int mi = 0; mi < 2; ++mi) {
                ah2[mi] = *(const short8*)&L[((wr * 2 + mi) * 2 + s2) * 512 + l * 8];
                al2[mi] = *(const short8*)&L[8192 + ((wr * 2 + mi) * 2 + s2) * 512 + l * 8];
            }
            #pragma unroll
            for (int ni = 0; ni < 2; ++ni) {
                bh2[ni] = *(const short8*)&L[16384 + ((wc * 2 + ni) * 2 + s2) * 512 + l * 8];
                bl2[ni] = *(const short8*)&L[20480 + ((wc * 2 + ni) * 2 + s2) * 512 + l * 8];
            }
            #pragma unroll
            for (int mi = 0; mi < 2; ++mi)
                #pragma unroll
                for (int ni = 0; ni < 2; ++ni) {
                    acc[mi][ni] = __builtin_amdgcn_mfma_f32_16x16x32_bf16(ah2[mi], bh2[ni], acc[mi][ni], 0, 0, 0);
                    acc[mi][ni] = __builtin_amdgcn_mfma_f32_16x16x32_bf16(ah2[mi], bl2[ni], acc[mi][ni], 0, 0, 0);
                    acc[mi][ni] = __builtin_amdgcn_mfma_f32_16x16x32_bf16(al2[mi], bh2[ni], acc[mi][ni], 0, 0, 0);
                }
        }
        __builtin_amdgcn_s_setprio(0);
        __builtin_amdgcn_sched_barrier(0);
    }
#undef STAGE

    // epilogue: fused W4 partial dots
    float bv[2], w4v[2];
    #pragma unroll
    for (int ni = 0; ni < 2; ++ni) {
        bv[ni]  = b3[bn + wc * 32 + ni * 16 + lr];
        w4v[ni] = W4[bn + wc * 32 + ni * 16 + lr];
    }
    #pragma unroll
    for (int mi = 0; mi < 2; ++mi) {
        float ps[4];
        #pragma unroll
        for (int r = 0; r < 4; ++r) {
            float acc_d = 0.f;
            #pragma unroll
            for (int ni = 0; ni < 2; ++ni) {
                float vv = acc[mi][ni][r] + bv[ni];
                vv = vv > 0.f ? vv : 0.f;
                acc_d += vv * w4v[ni];
            }
            ps[r] = acc_d;
        }
        #pragma unroll
        for (int r = 0; r < 4; ++r) {
            #pragma unroll
            for (int m2 = 1; m2 < 16; m2 <<= 1) ps[r] += __shfl_xor(ps[r], m2, 64);
        }
        if (lr == 0) {
            #pragma unroll
            for (int r = 0; r < 4; ++r) {
                int row = bm + wr * 32 + mi * 16 + lk * 4 + r;
                partial[(size_t)row * 32 + by * 2 + wc] = ps[r];
            }
        }
    }
}

// ---------------- ysum: y[r] = sum(partial[r][:]) + b4 ----------------
__global__ __launch_bounds__(256) void ysum_k(const float* __restrict__ partial,
                                              const float* __restrict__ b4,
                                              float* __restrict__ y) {
    int r = blockIdx.x * 256 + threadIdx.x;
    float s = 0.f;
    #pragma unroll
    for (int q = 0; q < 8; ++q) {
        float4 v = *(const float4*)&partial[(size_t)r * 32 + q * 4];
        s += v.x + v.y + v.z + v.w;
    }
    y[r] = s + b4[0];
}

extern "C" void kernel_launch(void* const* d_in, const int* in_sizes, int n_in,
                              void* d_out, int out_size, void* d_ws, size_t ws_size,
                              hipStream_t stream) {
    const float* X  = (const float*)d_in[0];
    const int*   p  = (const int*)d_in[1];
    const float* W1 = (const float*)d_in[2];
    const float* b1 = (const float*)d_in[3];
    const float* W2 = (const float*)d_in[4];
    const float* b2 = (const float*)d_in[5];
    const float* W3 = (const float*)d_in[6];
    const float* b3 = (const float*)d_in[7];
    const float* W4 = (const float*)d_in[8];
    const float* b4 = (const float*)d_in[9];
    float* out = (float*)d_out;

    char* ws = (char*)d_ws;
    size_t off = 0;
    float* psum = (float*)(ws + off); off += (size_t)NCH * PP * 4;
    unsigned short* h2h = (unsigned short*)(ws + off); off += (size_t)PP * HH * 2;
    unsigned short* h2l = (unsigned short*)(ws + off); off += (size_t)PP * HH * 2;
    unsigned short* w2h = (unsigned short*)(ws + off); off += (size_t)HH * HH * 2;
    unsigned short* w2l = (unsigned short*)(ws + off); off += (size_t)HH * HH * 2;
    unsigned short* w3h = (unsigned short*)(ws + off); off += (size_t)HH * HH * 2;
    unsigned short* w3l = (unsigned short*)(ws + off); off += (size_t)HH * HH * 2;
    float* partial = (float*)(ws + off); off += (size_t)PP * 32 * 4;

    pre_k<<<1024, 256, 0, stream>>>(X, p, psum, W2, w2h, w2l, W3, w3h, w3l);
    gemm1_k<<<256, 512, 0, stream>>>(psum, W1, b1, w2h, w2l, b2, h2h, h2l);
    gemm2_k<<<256, 512, 0, stream>>>(h2h, h2l, w3h, w3l, b3, W4, partial);
    ysum_k<<<PP / 256, 256, 0, stream>>>(partial, b4, out);
}